// Round 5
// baseline (373.312 us; speedup 1.0000x reference)
//
#include <hip/hip_runtime.h>
#include <hip/hip_bf16.h>
#include <stdint.h>

typedef __attribute__((ext_vector_type(4))) float f32x4;
typedef __attribute__((ext_vector_type(16))) float f32x16;
typedef __attribute__((ext_vector_type(8))) short short8;
typedef __attribute__((ext_vector_type(2))) int int2v;

#define DEV static __device__ __forceinline__

DEV unsigned short f2bf(float f) {
  unsigned u = __float_as_uint(f);
  u += 0x7fffu + ((u >> 16) & 1u);
  return (unsigned short)(u >> 16);
}

DEV uint32_t cvtpk(float a, float b) {  // {lo: bf16(a), hi: bf16(b)}
  uint32_t r;
  asm("v_cvt_pk_bf16_f32 %0, %1, %2" : "=v"(r) : "v"(a), "v"(b));
  return r;
}

// v_permlane32_swap_b32: r.x = {a[0:31], b[0:31] in hi lanes}, r.y = {a[32:63] in lo lanes, b[32:63]}
DEV int2v pl32(int a, int b) {
  return __builtin_amdgcn_permlane32_swap(a, b, false, false);
}

typedef const __attribute__((address_space(1))) void* gas_ptr;
typedef __attribute__((address_space(3))) void* las_ptr;

DEV void gload_lds16(const void* g, void* l) {
  __builtin_amdgcn_global_load_lds((gas_ptr)g, (las_ptr)l, 16, 0, 0);
}

// ------------- weight transpose+convert: src f32 [1024 k][1024 n] -> dst bf16 [n][k], 7 in one ----
struct TcvtArgs {
  const float* src[7];
  unsigned short* dst[7];
  int stride[7];
  int koff[7];
};

__global__ __launch_bounds__(256) void tcvt_kernel(TcvtArgs a) {
  const int which = blockIdx.z;
  const float* __restrict__ src = a.src[which];
  unsigned short* __restrict__ dst = a.dst[which];
  const int dstStride = a.stride[which], kOff = a.koff[which];
  __shared__ float tile[32][33];
  int tx = threadIdx.x & 31;   // 0..31
  int ty = threadIdx.x >> 5;   // 0..7
  int n0 = blockIdx.x * 32;
  int k0 = blockIdx.y * 32;
#pragma unroll
  for (int i = 0; i < 4; i++)
    tile[ty + 8 * i][tx] = src[(size_t)(k0 + ty + 8 * i) * 1024 + n0 + tx];
  __syncthreads();
#pragma unroll
  for (int i = 0; i < 4; i++) {
    int n = n0 + ty + 8 * i;
    dst[(size_t)n * dstStride + kOff + k0 + tx] = f2bf(tile[tx][ty + 8 * i]);
  }
}

// ---------------- merged Q/K/V projection GEMM (128^2), A staged as f32 via global_load_lds ----
// C[8192 x 1024] = concat_k(A1,A2) @ W  (A1,A2 = ORIGINAL f32 activations; W transposed bf16)
// R4 lesson: reg-staging A (load->cvt->ds_write) puts HBM latency on the K-loop critical path
// (227us).  Fix: keep global_load_lds as the transport (loads drain at the barrier, covered by
// TLP exactly like the 136us bf16 version) but stage A in *f32* and convert to bf16 at
// fragment-read time (2x ds_read_b128 + 4x v_cvt_pk per fragment).  Deletes the 301MB cvt pass.
// LDS 24KB.  XCD-chunked swizzle keeps the 1MB f32 A-slab L2-resident across its 8 nt-blocks.
struct G3Args {
  const float* A1[3];
  const float* A2[3];
  const unsigned short* WT[3];
  unsigned short* out[3];
};

__global__ __launch_bounds__(256) void gemm3_kernel(G3Args g) {
  __shared__ float Asf[128 * 32];
  __shared__ unsigned short Bs[128 * 32];
  const int orig = blockIdx.x;
  const int swz = (orig & 7) * 192 + (orig >> 3);  // 1536 blocks, bijective
  const int which = swz >> 9;
  const int bid = swz & 511;
  const float* __restrict__ A1 = g.A1[which];
  const float* __restrict__ A2 = g.A2[which];
  const unsigned short* __restrict__ WT = g.WT[which];
  unsigned short* __restrict__ outp = g.out[which];

  const int tid = threadIdx.x;
  const int lane = tid & 63;
  const int w = tid >> 6;
  const int mt = bid >> 3, nt = bid & 7;
  const int m0 = mt * 128, n0 = nt * 128;

  // B staging (bf16): wave stripes, 8 bf16 per thread per gload
  const int srow = (w << 4) + (lane >> 2);
  const int scol = (lane & 3) << 3;
  // A staging (f32): 4 rounds x 32 rows; 8 threads per row, 4 f32 per thread
  const int farow = tid >> 3;        // 0..31
  const int facol = (tid & 7) << 2;  // 0..28

  f32x4 zero4 = {0.f, 0.f, 0.f, 0.f};
  f32x4 acc[4][4];
#pragma unroll
  for (int mi = 0; mi < 4; mi++)
#pragma unroll
    for (int ni = 0; ni < 4; ni++) acc[mi][ni] = zero4;

  const int wr = w >> 1, wc = w & 1;
  const int arow = (wr << 6) + (lane & 15);
  const int brow = (wc << 6) + (lane & 15);
  const int kcol = (lane >> 4) << 3;  // k-offset 0/8/16/24 (elements)

  for (int kt = 0; kt < 64; kt++) {
    const int kk = kt << 5;
    const float* Af;
    int ka;
    if (kk < 1024) { Af = A1; ka = kk; } else { Af = A2; ka = kk - 1024; }
#pragma unroll
    for (int r = 0; r < 4; r++)
      gload_lds16(Af + (size_t)(m0 + r * 32 + farow) * 1024 + ka + facol,
                  &Asf[r * 1024 + tid * 4]);
#pragma unroll
    for (int p = 0; p < 2; p++) {
      const unsigned short* gp = WT + (size_t)(n0 + p * 64 + srow) * 2048 + kk + scol;
      gload_lds16(gp, &Bs[(p * 64 + srow) * 32 + scol]);
    }
    __syncthreads();

    short8 av[4], bv[4];
#pragma unroll
    for (int mi = 0; mi < 4; mi++) {
      const float4 lo = *reinterpret_cast<const float4*>(&Asf[(arow + mi * 16) * 32 + kcol]);
      const float4 hi = *reinterpret_cast<const float4*>(&Asf[(arow + mi * 16) * 32 + kcol + 4]);
      union { uint32_t u[4]; short8 v; } pk;
      pk.u[0] = cvtpk(lo.x, lo.y);
      pk.u[1] = cvtpk(lo.z, lo.w);
      pk.u[2] = cvtpk(hi.x, hi.y);
      pk.u[3] = cvtpk(hi.z, hi.w);
      av[mi] = pk.v;
    }
#pragma unroll
    for (int ni = 0; ni < 4; ni++)
      bv[ni] = *reinterpret_cast<const short8*>(&Bs[(brow + ni * 16) * 32 + kcol]);
#pragma unroll
    for (int mi = 0; mi < 4; mi++)
#pragma unroll
      for (int ni = 0; ni < 4; ni++)
        acc[mi][ni] = __builtin_amdgcn_mfma_f32_16x16x32_bf16(av[mi], bv[ni], acc[mi][ni], 0, 0, 0);
    __syncthreads();
  }

  // epilogue: D layout col = lane&15, row = (lane>>4)*4 + reg
#pragma unroll
  for (int mi = 0; mi < 4; mi++) {
#pragma unroll
    for (int ni = 0; ni < 4; ni++) {
      const int col = n0 + (wc << 6) + ni * 16 + (lane & 15);
      const int rbase = m0 + (wr << 6) + mi * 16 + ((lane >> 4) << 2);
      const int h = col >> 6, d = col & 63;
      if (which < 2) {
#pragma unroll
        for (int r = 0; r < 4; r++) {
          const int m = rbase + r;
          const int b = m >> 11, l = m & 2047;
          outp[((size_t)((b * 16 + h) * 2048 + l)) * 64 + d] = f2bf(acc[mi][ni][r]);
        }
      } else {
        // V tiled: [bh][l/32][d][l%32], tile = 64x32 = 4KB contiguous
        const int m = rbase;
        const int b = m >> 11, l = m & 2047;
        const int bh = b * 16 + h;
        ushort4 o;
        o.x = f2bf(acc[mi][ni][0]);
        o.y = f2bf(acc[mi][ni][1]);
        o.z = f2bf(acc[mi][ni][2]);
        o.w = f2bf(acc[mi][ni][3]);
        *reinterpret_cast<ushort4*>(
            outp + (size_t)(bh * 64 + (l >> 5)) * 2048 + d * 32 + (l & 31)) = o;
      }
    }
  }
}

// ---------------- fc GEMM: C[8192 x 1024] = A @ W + q_a + q_s (residual fused), f32 out -------
__global__ __launch_bounds__(256) void gemmfc_kernel(const unsigned short* __restrict__ A1,
                                                     const unsigned short* __restrict__ WT,
                                                     const float* __restrict__ qa,
                                                     const float* __restrict__ qs,
                                                     float* __restrict__ outp) {
  __shared__ unsigned short As[128 * 32];
  __shared__ unsigned short Bs[128 * 32];
  const int orig = blockIdx.x;
  const int bid = (orig & 7) * 64 + (orig >> 3);  // 512 blocks, bijective XCD chunk
  const int tid = threadIdx.x;
  const int lane = tid & 63;
  const int w = tid >> 6;
  const int mt = bid >> 3, nt = bid & 7;
  const int m0 = mt * 128, n0 = nt * 128;

  const int srow = (w << 4) + (lane >> 2);
  const int scol = (lane & 3) << 3;

  f32x4 zero4 = {0.f, 0.f, 0.f, 0.f};
  f32x4 acc[4][4];
#pragma unroll
  for (int mi = 0; mi < 4; mi++)
#pragma unroll
    for (int ni = 0; ni < 4; ni++) acc[mi][ni] = zero4;

  const int wr = w >> 1, wc = w & 1;
  const int arow = (wr << 6) + (lane & 15);
  const int brow = (wc << 6) + (lane & 15);
  const int kcol = (lane >> 4) << 3;

  for (int kt = 0; kt < 32; kt++) {
    const int kk = kt << 5;
#pragma unroll
    for (int p = 0; p < 2; p++) {
      const unsigned short* gp = A1 + (size_t)(m0 + p * 64 + srow) * 1024 + kk + scol;
      gload_lds16(gp, &As[(p * 64 + srow) * 32 + scol]);
    }
#pragma unroll
    for (int p = 0; p < 2; p++) {
      const unsigned short* gp = WT + (size_t)(n0 + p * 64 + srow) * 1024 + kk + scol;
      gload_lds16(gp, &Bs[(p * 64 + srow) * 32 + scol]);
    }
    __syncthreads();

    short8 av[4], bv[4];
#pragma unroll
    for (int mi = 0; mi < 4; mi++)
      av[mi] = *reinterpret_cast<const short8*>(&As[(arow + mi * 16) * 32 + kcol]);
#pragma unroll
    for (int ni = 0; ni < 4; ni++)
      bv[ni] = *reinterpret_cast<const short8*>(&Bs[(brow + ni * 16) * 32 + kcol]);
#pragma unroll
    for (int mi = 0; mi < 4; mi++)
#pragma unroll
      for (int ni = 0; ni < 4; ni++)
        acc[mi][ni] = __builtin_amdgcn_mfma_f32_16x16x32_bf16(av[mi], bv[ni], acc[mi][ni], 0, 0, 0);
    __syncthreads();
  }

#pragma unroll
  for (int mi = 0; mi < 4; mi++) {
#pragma unroll
    for (int ni = 0; ni < 4; ni++) {
      const int col = n0 + (wc << 6) + ni * 16 + (lane & 15);
      const int rbase = m0 + (wr << 6) + mi * 16 + ((lane >> 4) << 2);
#pragma unroll
      for (int r = 0; r < 4; r++) {
        const size_t idx = (size_t)(rbase + r) * 1024 + col;
        outp[idx] = acc[mi][ni][r] + qa[idx] + qs[idx];
      }
    }
  }
}

// ---------------- flash attention, LDS-staged K/V shared by 4 waves ----------------
// Q,K: bf16 [bh][l][64]; Vt: bf16 tiled [bh][l/32][d][l%32]; O: bf16 [b*2048+l][h*64+d]
__global__ __launch_bounds__(256) void attn_kernel(const unsigned short* __restrict__ Q,
                                                   const unsigned short* __restrict__ K,
                                                   const unsigned short* __restrict__ Vt,
                                                   unsigned short* __restrict__ O) {
  __shared__ unsigned short Ks[2][2048];
  __shared__ unsigned short Vs[2][2048];
  const int tid = threadIdx.x;
  const int lane = tid & 63;
  const int w = tid >> 6;      // 0..3 = q-tile
  const int n = blockIdx.x;
  const int bh = (n & 7) * 8 + (n >> 7);   // XCD c owns bh [8c, 8c+8): 4MB K/V per L2
  const int qg = (n >> 3) & 15;
  const int q0 = qg * 128 + w * 32;
  const int lo = lane & 31, hi = lane >> 5;

  const unsigned short* qp = Q + ((size_t)bh * 2048 + q0 + lo) * 64 + (hi << 3);
  short8 qf[4];
#pragma unroll
  for (int c = 0; c < 4; c++)
    qf[c] = *reinterpret_cast<const short8*>(qp + c * 16);

  f32x16 o0 = {0.f,0.f,0.f,0.f,0.f,0.f,0.f,0.f,0.f,0.f,0.f,0.f,0.f,0.f,0.f,0.f};
  f32x16 o1 = {0.f,0.f,0.f,0.f,0.f,0.f,0.f,0.f,0.f,0.f,0.f,0.f,0.f,0.f,0.f,0.f};
  float mrun = -1e30f, lsum = 0.0f;
  const float KS = 1.44269504088896f / 16.0f;  // log2(e)/SCALE

  const char* Kg = (const char*)(K + (size_t)bh * 2048 * 64);
  const char* Vg = (const char*)(Vt + (size_t)bh * 131072);

  const int p16 = tid * 16;
  const int lswz = p16 ^ (((p16 >> 7) & 7) << 4);  // logical byte within tile
  const int koff = lswz;                            // K: logical == global layout
  const int voff = (lswz >> 7) * 64 + ((lswz >> 6) & 1) * 2048 + (lswz & 63);

  const int sK = (lo & 7) << 4;
  int kix[4];
#pragma unroll
  for (int c = 0; c < 4; c++)
    kix[c] = ((lo * 128 + hi * 16 + c * 32) ^ sK) >> 1;   // K[key=lo][d=hi*8 + c*16]
  int vix[4];
  vix[0] = ((lo * 128 + hi * 16) ^ sK) >> 1;        // V[d=lo   ][key=hi*8]
  vix[1] = ((lo * 128 + 32 + hi * 16) ^ sK) >> 1;   // V[d=lo   ][key=hi*8+16]
  vix[2] = ((lo * 128 + 64 + hi * 16) ^ sK) >> 1;   // V[d=lo+32][key=hi*8]
  vix[3] = ((lo * 128 + 96 + hi * 16) ^ sK) >> 1;   // V[d=lo+32][key=hi*8+16]

  auto STAGE = [&](int kt, int buf) {
    gload_lds16(Kg + (size_t)kt * 4096 + koff, &Ks[buf][tid * 8]);
    gload_lds16(Vg + (size_t)kt * 4096 + voff, &Vs[buf][tid * 8]);
  };

  STAGE(0, 0);
  __syncthreads();

  for (int kt = 0; kt < 64; kt++) {
    const int buf = kt & 1;
    const int nx = (kt < 63) ? kt + 1 : 63;
    STAGE(nx, buf ^ 1);  // in flight across this iteration; drained by __syncthreads

    short8 kc[4], vc[4];
#pragma unroll
    for (int c = 0; c < 4; c++)
      kc[c] = *reinterpret_cast<const short8*>(&Ks[buf][kix[c]]);
#pragma unroll
    for (int c = 0; c < 4; c++)
      vc[c] = *reinterpret_cast<const short8*>(&Vs[buf][vix[c]]);

    // QK^T (swapped: A=K so D rows = keys, D cols = q)
    f32x16 s = {0.f,0.f,0.f,0.f,0.f,0.f,0.f,0.f,0.f,0.f,0.f,0.f,0.f,0.f,0.f,0.f};
    __builtin_amdgcn_s_setprio(1);
#pragma unroll
    for (int c = 0; c < 4; c++)
      s = __builtin_amdgcn_mfma_f32_32x32x16_bf16(kc[c], qf[c], s, 0, 0, 0);
    __builtin_amdgcn_s_setprio(0);

    // online softmax (defer-max T13); cross-lane merges via permlane32_swap
    float m01 = fmaxf(s[0], s[1]), m23 = fmaxf(s[2], s[3]);
    float m45 = fmaxf(s[4], s[5]), m67 = fmaxf(s[6], s[7]);
    float m89 = fmaxf(s[8], s[9]), mab = fmaxf(s[10], s[11]);
    float mcd = fmaxf(s[12], s[13]), mef = fmaxf(s[14], s[15]);
    float cmax = fmaxf(fmaxf(fmaxf(m01, m23), fmaxf(m45, m67)),
                       fmaxf(fmaxf(m89, mab), fmaxf(mcd, mef)));
    {
      int2v mm = pl32(__float_as_int(cmax), __float_as_int(cmax));
      cmax = fmaxf(__int_as_float(mm.x), __int_as_float(mm.y));
    }

    if (__any(cmax > mrun + 128.0f)) {  // 128 raw = 8 post-scale nats
      const float mnew = fmaxf(mrun, cmax);
      const float alpha = __builtin_amdgcn_exp2f((mrun - mnew) * KS);
      lsum *= alpha;
#pragma unroll
      for (int r = 0; r < 16; r++) {
        const int row = (r & 3) + ((r >> 2) << 3) + (hi << 2);
        const float ar = __shfl(alpha, row);
        o0[r] *= ar;
        o1[r] *= ar;
      }
      mrun = mnew;
    }

    float pr[16];
    const float mk = mrun * KS;
#pragma unroll
    for (int r = 0; r < 16; r++)
      pr[r] = __builtin_amdgcn_exp2f(__builtin_fmaf(s[r], KS, -mk));
    float c01 = (pr[0] + pr[1]) + (pr[2] + pr[3]);
    float c23 = (pr[4] + pr[5]) + (pr[6] + pr[7]);
    float c45 = (pr[8] + pr[9]) + (pr[10] + pr[11]);
    float c67 = (pr[12] + pr[13]) + (pr[14] + pr[15]);
    float csum = (c01 + c23) + (c45 + c67);
    {
      int2v ss = pl32(__float_as_int(csum), __float_as_int(csum));
      csum = __int_as_float(ss.x) + __int_as_float(ss.y);
    }
    lsum += csum;

    // pack P -> bf16 PV A-fragments via permlane32_swap
    const uint32_t c0 = cvtpk(pr[0], pr[1]),   c1 = cvtpk(pr[2], pr[3]);
    const uint32_t c2 = cvtpk(pr[4], pr[5]),   c3 = cvtpk(pr[6], pr[7]);
    const uint32_t c4 = cvtpk(pr[8], pr[9]),   c5 = cvtpk(pr[10], pr[11]);
    const uint32_t c6 = cvtpk(pr[12], pr[13]), c7 = cvtpk(pr[14], pr[15]);
    int2v s02 = pl32((int)c0, (int)c2);
    int2v s13 = pl32((int)c1, (int)c3);
    int2v s46 = pl32((int)c4, (int)c6);
    int2v s57 = pl32((int)c5, (int)c7);
    union { uint32_t u[4]; short8 v; } pa, pb;
    pa.u[0] = (uint32_t)s02.x; pa.u[1] = (uint32_t)s13.x;
    pa.u[2] = (uint32_t)s02.y; pa.u[3] = (uint32_t)s13.y;
    pb.u[0] = (uint32_t)s46.x; pb.u[1] = (uint32_t)s57.x;
    pb.u[2] = (uint32_t)s46.y; pb.u[3] = (uint32_t)s57.y;

    // PV
    __builtin_amdgcn_s_setprio(1);
    o0 = __builtin_amdgcn_mfma_f32_32x32x16_bf16(pa.v, vc[0], o0, 0, 0, 0);
    o0 = __builtin_amdgcn_mfma_f32_32x32x16_bf16(pb.v, vc[1], o0, 0, 0, 0);
    o1 = __builtin_amdgcn_mfma_f32_32x32x16_bf16(pa.v, vc[2], o1, 0, 0, 0);
    o1 = __builtin_amdgcn_mfma_f32_32x32x16_bf16(pb.v, vc[3], o1, 0, 0, 0);
    __builtin_amdgcn_s_setprio(0);

    __syncthreads();  // drains stage (vmcnt 0) + this wave's ds_reads (lgkmcnt 0)
  }

  const int b = bh >> 4, h = bh & 15;
#pragma unroll
  for (int r = 0; r < 16; r++) {
    const int row = (r & 3) + ((r >> 2) << 3) + (hi << 2);
    const float lr = __shfl(lsum, row);
    const float inv = __builtin_amdgcn_rcpf(lr);
    const size_t base = ((size_t)b * 2048 + q0 + row) * 1024 + h * 64 + lo;
    O[base] = f2bf(o0[r] * inv);
    O[base + 32] = f2bf(o1[r] * inv);
  }
}

// ---------------- LayerNorm (residual already folded into fc by gemmfc) ----------------
__global__ __launch_bounds__(256) void ln_kernel(const float* __restrict__ fc,
                                                 const float* __restrict__ gamma,
                                                 const float* __restrict__ beta,
                                                 float* __restrict__ out) {
  const int m = blockIdx.x;
  const int t = threadIdx.x;
  const size_t base = (size_t)m * 1024 + t * 4;
  float4 x = *reinterpret_cast<const float4*>(fc + base);
  float s1 = x.x + x.y + x.z + x.w;
  float s2 = x.x * x.x + x.y * x.y + x.z * x.z + x.w * x.w;
#pragma unroll
  for (int off = 1; off < 64; off <<= 1) {
    s1 += __shfl_xor(s1, off);
    s2 += __shfl_xor(s2, off);
  }
  __shared__ float sh[8];
  const int w = t >> 6, lane = t & 63;
  if (lane == 0) { sh[w] = s1; sh[4 + w] = s2; }
  __syncthreads();
  s1 = sh[0] + sh[1] + sh[2] + sh[3];
  s2 = sh[4] + sh[5] + sh[6] + sh[7];
  const float mu = s1 * (1.0f / 1024.0f);
  const float var = s2 * (1.0f / 1024.0f) - mu * mu;
  const float rs = rsqrtf(var + 1e-6f);
  const float4 g = *reinterpret_cast<const float4*>(gamma + t * 4);
  const float4 be = *reinterpret_cast<const float4*>(beta + t * 4);
  float4 y;
  y.x = (x.x - mu) * rs * g.x + be.x;
  y.y = (x.y - mu) * rs * g.y + be.y;
  y.z = (x.z - mu) * rs * g.z + be.z;
  y.w = (x.w - mu) * rs * g.w + be.w;
  *reinterpret_cast<float4*>(out + base) = y;
}

__global__ void sentinel_kernel(float* out, int n) {
  int i = blockIdx.x * blockDim.x + threadIdx.x;
  if (i < n) out[i] = 1234.5f;
}

extern "C" void kernel_launch(void* const* d_in, const int* in_sizes, int n_in,
                              void* d_out, int out_size, void* d_ws, size_t ws_size,
                              hipStream_t stream) {
  const size_t MB = 1024ull * 1024ull;
  if (ws_size < 174 * MB) {  // distinctive failure mode if scratch too small
    sentinel_kernel<<<(out_size + 255) / 256, 256, 0, stream>>>((float*)d_out, out_size);
    return;
  }
  const float* fin[6];
  for (int i = 0; i < 6; i++) fin[i] = (const float*)d_in[i];
  const float* Wf[7];
  for (int i = 0; i < 7; i++) Wf[i] = (const float*)d_in[6 + i];
  const float* gamma = (const float*)d_in[13];
  const float* beta = (const float*)d_in[14];

  char* ws = (char*)d_ws;
  unsigned short* WqT = (unsigned short*)(ws + 96 * MB);   // [1024][2048]
  unsigned short* WkT = (unsigned short*)(ws + 100 * MB);
  unsigned short* WvT = (unsigned short*)(ws + 104 * MB);
  unsigned short* WfcT = (unsigned short*)(ws + 108 * MB); // [1024][1024]
  unsigned short* Qb = (unsigned short*)(ws + 110 * MB);   // [64][2048][64]
  unsigned short* Kb = (unsigned short*)(ws + 126 * MB);
  unsigned short* Vtb = (unsigned short*)(ws + 142 * MB);  // [64][64][64][32] tiled
  unsigned short* Ob = (unsigned short*)(ws + 158 * MB);   // [8192][1024]
  float* fcout = (float*)(ws + 16 * MB);

  TcvtArgs ta;
  const int wsel[7] = {0, 3, 1, 4, 2, 5, 6};
  unsigned short* wdst[7] = {WqT, WqT, WkT, WkT, WvT, WvT, WfcT};
  for (int i = 0; i < 7; i++) {
    ta.src[i] = Wf[wsel[i]];
    ta.dst[i] = wdst[i];
    ta.stride[i] = (i < 6) ? 2048 : 1024;
    ta.koff[i] = (i < 6) ? ((i & 1) ? 1024 : 0) : 0;
  }
  tcvt_kernel<<<dim3(32, 32, 7), 256, 0, stream>>>(ta);

  G3Args g3;
  g3.A1[0] = fin[0]; g3.A2[0] = fin[3]; g3.WT[0] = WqT; g3.out[0] = Qb;
  g3.A1[1] = fin[1]; g3.A2[1] = fin[4]; g3.WT[1] = WkT; g3.out[1] = Kb;
  g3.A1[2] = fin[2]; g3.A2[2] = fin[5]; g3.WT[2] = WvT; g3.out[2] = Vtb;
  gemm3_kernel<<<1536, 256, 0, stream>>>(g3);

  attn_kernel<<<1024, 256, 0, stream>>>(Qb, Kb, Vtb, Ob);

  gemmfc_kernel<<<512, 256, 0, stream>>>(Ob, WfcT, fin[0], fin[3], fcout);

  ln_kernel<<<8192, 256, 0, stream>>>(fcout, gamma, beta, (float*)d_out);
}

// Round 6
// 366.434 us; speedup vs baseline: 1.0188x; 1.0188x over previous
//
#include <hip/hip_runtime.h>
#include <hip/hip_bf16.h>
#include <stdint.h>

typedef __attribute__((ext_vector_type(4))) float f32x4;
typedef __attribute__((ext_vector_type(16))) float f32x16;
typedef __attribute__((ext_vector_type(8))) short short8;
typedef __attribute__((ext_vector_type(2))) int int2v;

#define DEV static __device__ __forceinline__

DEV unsigned short f2bf(float f) {
  unsigned u = __float_as_uint(f);
  u += 0x7fffu + ((u >> 16) & 1u);
  return (unsigned short)(u >> 16);
}

DEV uint32_t cvtpk(float a, float b) {  // {lo: bf16(a), hi: bf16(b)}
  uint32_t r;
  asm("v_cvt_pk_bf16_f32 %0, %1, %2" : "=v"(r) : "v"(a), "v"(b));
  return r;
}

// v_permlane32_swap_b32: r.x = {a[0:31], b[0:31] in hi lanes}, r.y = {a[32:63] in lo lanes, b[32:63]}
DEV int2v pl32(int a, int b) {
  return __builtin_amdgcn_permlane32_swap(a, b, false, false);
}

typedef const __attribute__((address_space(1))) void* gas_ptr;
typedef __attribute__((address_space(3))) void* las_ptr;

DEV void gload_lds16(const void* g, void* l) {
  __builtin_amdgcn_global_load_lds((gas_ptr)g, (las_ptr)l, 16, 0, 0);
}

// ------------- weight transpose+convert: src f32 [1024 k][1024 n] -> dst bf16 [n][k], 7 in one ----
struct TcvtArgs {
  const float* src[7];
  unsigned short* dst[7];
  int stride[7];
  int koff[7];
};

__global__ __launch_bounds__(256) void tcvt_kernel(TcvtArgs a) {
  const int which = blockIdx.z;
  const float* __restrict__ src = a.src[which];
  unsigned short* __restrict__ dst = a.dst[which];
  const int dstStride = a.stride[which], kOff = a.koff[which];
  __shared__ float tile[32][33];
  int tx = threadIdx.x & 31;   // 0..31
  int ty = threadIdx.x >> 5;   // 0..7
  int n0 = blockIdx.x * 32;
  int k0 = blockIdx.y * 32;
#pragma unroll
  for (int i = 0; i < 4; i++)
    tile[ty + 8 * i][tx] = src[(size_t)(k0 + ty + 8 * i) * 1024 + n0 + tx];
  __syncthreads();
#pragma unroll
  for (int i = 0; i < 4; i++) {
    int n = n0 + ty + 8 * i;
    dst[(size_t)n * dstStride + kOff + k0 + tx] = f2bf(tile[tx][ty + 8 * i]);
  }
}

// ---------------- merged Q/K/V projection GEMM (128^2), A staged as f32 via global_load_lds ----
// C[8192 x 1024] = concat_k(A1,A2) @ W  (A1,A2 = ORIGINAL f32 activations; W transposed bf16)
// A-tile rows are 128B f32 -> unswizzled fragment read is a 16-way bank conflict (R5: 4.4e7
// conflicts, 236us).  Fix (T2, same involution as attn's K tile): phys_byte = logical ^
// ((row&7)<<4), applied as inverse-swizzled GLOBAL source at staging (linear LDS dest,
// rule #21) + XOR on the full byte offset at fragment-read.  bf16 cvt at read time
// (4x v_cvt_pk per fragment).  Deletes the 301MB cvt pass.  LDS 24KB.
struct G3Args {
  const float* A1[3];
  const float* A2[3];
  const unsigned short* WT[3];
  unsigned short* out[3];
};

__global__ __launch_bounds__(256) void gemm3_kernel(G3Args g) {
  __shared__ float Asf[128 * 32];
  __shared__ unsigned short Bs[128 * 32];
  const int orig = blockIdx.x;
  const int swz = (orig & 7) * 192 + (orig >> 3);  // 1536 blocks, bijective
  const int which = swz >> 9;
  const int bid = swz & 511;
  const float* __restrict__ A1 = g.A1[which];
  const float* __restrict__ A2 = g.A2[which];
  const unsigned short* __restrict__ WT = g.WT[which];
  unsigned short* __restrict__ outp = g.out[which];

  const int tid = threadIdx.x;
  const int lane = tid & 63;
  const int w = tid >> 6;
  const int mt = bid >> 3, nt = bid & 7;
  const int m0 = mt * 128, n0 = nt * 128;

  // B staging (bf16): wave stripes, 8 bf16 per thread per gload
  const int srow = (w << 4) + (lane >> 2);
  const int scol = (lane & 3) << 3;
  // A staging (f32): 4 rounds x 32 rows; 8 threads/row, 4 f32/thread; linear LDS dest at
  // byte row*128 + (tid&7)*16; source col inverse-swizzled by ((row&7)<<2) f32 elements
  const int farow = tid >> 3;                                   // 0..31
  const int facol = (((tid & 7) << 2) ^ ((farow & 7) << 2));    // f32 elements, pre-swizzled

  f32x4 zero4 = {0.f, 0.f, 0.f, 0.f};
  f32x4 acc[4][4];
#pragma unroll
  for (int mi = 0; mi < 4; mi++)
#pragma unroll
    for (int ni = 0; ni < 4; ni++) acc[mi][ni] = zero4;

  const int wr = w >> 1, wc = w & 1;
  const int arow = (wr << 6) + (lane & 15);
  const int brow = (wc << 6) + (lane & 15);
  const int kcol = (lane >> 4) << 3;  // k-offset 0/8/16/24 (elements)

  // fragment-read byte offsets within the 128B row, XOR-swizzled.
  // (arow + mi*16) & 7 == arow & 7, so the swizzle is mi-invariant; XOR by a multiple of 16
  // keeps each 16B float4 block contiguous in logical space.
  const int sAb = (arow & 7) << 4;
  const int cA0 = ((kcol << 2)) ^ sAb;
  const int cA1 = ((kcol << 2) + 16) ^ sAb;

  for (int kt = 0; kt < 64; kt++) {
    const int kk = kt << 5;
    const float* Af;
    int ka;
    if (kk < 1024) { Af = A1; ka = kk; } else { Af = A2; ka = kk - 1024; }
#pragma unroll
    for (int r = 0; r < 4; r++)
      gload_lds16(Af + (size_t)(m0 + r * 32 + farow) * 1024 + ka + facol,
                  &Asf[r * 1024 + tid * 4]);
#pragma unroll
    for (int p = 0; p < 2; p++) {
      const unsigned short* gp = WT + (size_t)(n0 + p * 64 + srow) * 2048 + kk + scol;
      gload_lds16(gp, &Bs[(p * 64 + srow) * 32 + scol]);
    }
    __syncthreads();

    short8 av[4], bv[4];
#pragma unroll
    for (int mi = 0; mi < 4; mi++) {
      const char* arp = reinterpret_cast<const char*>(Asf) + (size_t)(arow + mi * 16) * 128;
      const float4 lo = *reinterpret_cast<const float4*>(arp + cA0);
      const float4 hi = *reinterpret_cast<const float4*>(arp + cA1);
      union { uint32_t u[4]; short8 v; } pk;
      pk.u[0] = cvtpk(lo.x, lo.y);
      pk.u[1] = cvtpk(lo.z, lo.w);
      pk.u[2] = cvtpk(hi.x, hi.y);
      pk.u[3] = cvtpk(hi.z, hi.w);
      av[mi] = pk.v;
    }
#pragma unroll
    for (int ni = 0; ni < 4; ni++)
      bv[ni] = *reinterpret_cast<const short8*>(&Bs[(brow + ni * 16) * 32 + kcol]);
#pragma unroll
    for (int mi = 0; mi < 4; mi++)
#pragma unroll
      for (int ni = 0; ni < 4; ni++)
        acc[mi][ni] = __builtin_amdgcn_mfma_f32_16x16x32_bf16(av[mi], bv[ni], acc[mi][ni], 0, 0, 0);
    __syncthreads();
  }

  // epilogue: D layout col = lane&15, row = (lane>>4)*4 + reg
#pragma unroll
  for (int mi = 0; mi < 4; mi++) {
#pragma unroll
    for (int ni = 0; ni < 4; ni++) {
      const int col = n0 + (wc << 6) + ni * 16 + (lane & 15);
      const int rbase = m0 + (wr << 6) + mi * 16 + ((lane >> 4) << 2);
      const int h = col >> 6, d = col & 63;
      if (which < 2) {
#pragma unroll
        for (int r = 0; r < 4; r++) {
          const int m = rbase + r;
          const int b = m >> 11, l = m & 2047;
          outp[((size_t)((b * 16 + h) * 2048 + l)) * 64 + d] = f2bf(acc[mi][ni][r]);
        }
      } else {
        // V tiled: [bh][l/32][d][l%32], tile = 64x32 = 4KB contiguous
        const int m = rbase;
        const int b = m >> 11, l = m & 2047;
        const int bh = b * 16 + h;
        ushort4 o;
        o.x = f2bf(acc[mi][ni][0]);
        o.y = f2bf(acc[mi][ni][1]);
        o.z = f2bf(acc[mi][ni][2]);
        o.w = f2bf(acc[mi][ni][3]);
        *reinterpret_cast<ushort4*>(
            outp + (size_t)(bh * 64 + (l >> 5)) * 2048 + d * 32 + (l & 31)) = o;
      }
    }
  }
}

// ---------------- fc GEMM: C[8192 x 1024] = A @ W + q_a + q_s (residual fused), f32 out -------
__global__ __launch_bounds__(256) void gemmfc_kernel(const unsigned short* __restrict__ A1,
                                                     const unsigned short* __restrict__ WT,
                                                     const float* __restrict__ qa,
                                                     const float* __restrict__ qs,
                                                     float* __restrict__ outp) {
  __shared__ unsigned short As[128 * 32];
  __shared__ unsigned short Bs[128 * 32];
  const int orig = blockIdx.x;
  const int bid = (orig & 7) * 64 + (orig >> 3);  // 512 blocks, bijective XCD chunk
  const int tid = threadIdx.x;
  const int lane = tid & 63;
  const int w = tid >> 6;
  const int mt = bid >> 3, nt = bid & 7;
  const int m0 = mt * 128, n0 = nt * 128;

  const int srow = (w << 4) + (lane >> 2);
  const int scol = (lane & 3) << 3;

  f32x4 zero4 = {0.f, 0.f, 0.f, 0.f};
  f32x4 acc[4][4];
#pragma unroll
  for (int mi = 0; mi < 4; mi++)
#pragma unroll
    for (int ni = 0; ni < 4; ni++) acc[mi][ni] = zero4;

  const int wr = w >> 1, wc = w & 1;
  const int arow = (wr << 6) + (lane & 15);
  const int brow = (wc << 6) + (lane & 15);
  const int kcol = (lane >> 4) << 3;

  for (int kt = 0; kt < 32; kt++) {
    const int kk = kt << 5;
#pragma unroll
    for (int p = 0; p < 2; p++) {
      const unsigned short* gp = A1 + (size_t)(m0 + p * 64 + srow) * 1024 + kk + scol;
      gload_lds16(gp, &As[(p * 64 + srow) * 32 + scol]);
    }
#pragma unroll
    for (int p = 0; p < 2; p++) {
      const unsigned short* gp = WT + (size_t)(n0 + p * 64 + srow) * 1024 + kk + scol;
      gload_lds16(gp, &Bs[(p * 64 + srow) * 32 + scol]);
    }
    __syncthreads();

    short8 av[4], bv[4];
#pragma unroll
    for (int mi = 0; mi < 4; mi++)
      av[mi] = *reinterpret_cast<const short8*>(&As[(arow + mi * 16) * 32 + kcol]);
#pragma unroll
    for (int ni = 0; ni < 4; ni++)
      bv[ni] = *reinterpret_cast<const short8*>(&Bs[(brow + ni * 16) * 32 + kcol]);
#pragma unroll
    for (int mi = 0; mi < 4; mi++)
#pragma unroll
      for (int ni = 0; ni < 4; ni++)
        acc[mi][ni] = __builtin_amdgcn_mfma_f32_16x16x32_bf16(av[mi], bv[ni], acc[mi][ni], 0, 0, 0);
    __syncthreads();
  }

#pragma unroll
  for (int mi = 0; mi < 4; mi++) {
#pragma unroll
    for (int ni = 0; ni < 4; ni++) {
      const int col = n0 + (wc << 6) + ni * 16 + (lane & 15);
      const int rbase = m0 + (wr << 6) + mi * 16 + ((lane >> 4) << 2);
#pragma unroll
      for (int r = 0; r < 4; r++) {
        const size_t idx = (size_t)(rbase + r) * 1024 + col;
        outp[idx] = acc[mi][ni][r] + qa[idx] + qs[idx];
      }
    }
  }
}

// ---------------- flash attention, LDS-staged K/V shared by 4 waves ----------------
// Q,K: bf16 [bh][l][64]; Vt: bf16 tiled [bh][l/32][d][l%32]; O: bf16 [b*2048+l][h*64+d]
__global__ __launch_bounds__(256) void attn_kernel(const unsigned short* __restrict__ Q,
                                                   const unsigned short* __restrict__ K,
                                                   const unsigned short* __restrict__ Vt,
                                                   unsigned short* __restrict__ O) {
  __shared__ unsigned short Ks[2][2048];
  __shared__ unsigned short Vs[2][2048];
  const int tid = threadIdx.x;
  const int lane = tid & 63;
  const int w = tid >> 6;      // 0..3 = q-tile
  const int n = blockIdx.x;
  const int bh = (n & 7) * 8 + (n >> 7);   // XCD c owns bh [8c, 8c+8): 4MB K/V per L2
  const int qg = (n >> 3) & 15;
  const int q0 = qg * 128 + w * 32;
  const int lo = lane & 31, hi = lane >> 5;

  const unsigned short* qp = Q + ((size_t)bh * 2048 + q0 + lo) * 64 + (hi << 3);
  short8 qf[4];
#pragma unroll
  for (int c = 0; c < 4; c++)
    qf[c] = *reinterpret_cast<const short8*>(qp + c * 16);

  f32x16 o0 = {0.f,0.f,0.f,0.f,0.f,0.f,0.f,0.f,0.f,0.f,0.f,0.f,0.f,0.f,0.f,0.f};
  f32x16 o1 = {0.f,0.f,0.f,0.f,0.f,0.f,0.f,0.f,0.f,0.f,0.f,0.f,0.f,0.f,0.f,0.f};
  float mrun = -1e30f, lsum = 0.0f;
  const float KS = 1.44269504088896f / 16.0f;  // log2(e)/SCALE

  const char* Kg = (const char*)(K + (size_t)bh * 2048 * 64);
  const char* Vg = (const char*)(Vt + (size_t)bh * 131072);

  const int p16 = tid * 16;
  const int lswz = p16 ^ (((p16 >> 7) & 7) << 4);  // logical byte within tile
  const int koff = lswz;                            // K: logical == global layout
  const int voff = (lswz >> 7) * 64 + ((lswz >> 6) & 1) * 2048 + (lswz & 63);

  const int sK = (lo & 7) << 4;
  int kix[4];
#pragma unroll
  for (int c = 0; c < 4; c++)
    kix[c] = ((lo * 128 + hi * 16 + c * 32) ^ sK) >> 1;   // K[key=lo][d=hi*8 + c*16]
  int vix[4];
  vix[0] = ((lo * 128 + hi * 16) ^ sK) >> 1;        // V[d=lo   ][key=hi*8]
  vix[1] = ((lo * 128 + 32 + hi * 16) ^ sK) >> 1;   // V[d=lo   ][key=hi*8+16]
  vix[2] = ((lo * 128 + 64 + hi * 16) ^ sK) >> 1;   // V[d=lo+32][key=hi*8]
  vix[3] = ((lo * 128 + 96 + hi * 16) ^ sK) >> 1;   // V[d=lo+32][key=hi*8+16]

  auto STAGE = [&](int kt, int buf) {
    gload_lds16(Kg + (size_t)kt * 4096 + koff, &Ks[buf][tid * 8]);
    gload_lds16(Vg + (size_t)kt * 4096 + voff, &Vs[buf][tid * 8]);
  };

  STAGE(0, 0);
  __syncthreads();

  for (int kt = 0; kt < 64; kt++) {
    const int buf = kt & 1;
    const int nx = (kt < 63) ? kt + 1 : 63;
    STAGE(nx, buf ^ 1);  // in flight across this iteration; drained by __syncthreads

    short8 kc[4], vc[4];
#pragma unroll
    for (int c = 0; c < 4; c++)
      kc[c] = *reinterpret_cast<const short8*>(&Ks[buf][kix[c]]);
#pragma unroll
    for (int c = 0; c < 4; c++)
      vc[c] = *reinterpret_cast<const short8*>(&Vs[buf][vix[c]]);

    // QK^T (swapped: A=K so D rows = keys, D cols = q)
    f32x16 s = {0.f,0.f,0.f,0.f,0.f,0.f,0.f,0.f,0.f,0.f,0.f,0.f,0.f,0.f,0.f,0.f};
    __builtin_amdgcn_s_setprio(1);
#pragma unroll
    for (int c = 0; c < 4; c++)
      s = __builtin_amdgcn_mfma_f32_32x32x16_bf16(kc[c], qf[c], s, 0, 0, 0);
    __builtin_amdgcn_s_setprio(0);

    // online softmax (defer-max T13); cross-lane merges via permlane32_swap
    float m01 = fmaxf(s[0], s[1]), m23 = fmaxf(s[2], s[3]);
    float m45 = fmaxf(s[4], s[5]), m67 = fmaxf(s[6], s[7]);
    float m89 = fmaxf(s[8], s[9]), mab = fmaxf(s[10], s[11]);
    float mcd = fmaxf(s[12], s[13]), mef = fmaxf(s[14], s[15]);
    float cmax = fmaxf(fmaxf(fmaxf(m01, m23), fmaxf(m45, m67)),
                       fmaxf(fmaxf(m89, mab), fmaxf(mcd, mef)));
    {
      int2v mm = pl32(__float_as_int(cmax), __float_as_int(cmax));
      cmax = fmaxf(__int_as_float(mm.x), __int_as_float(mm.y));
    }

    if (__any(cmax > mrun + 128.0f)) {  // 128 raw = 8 post-scale nats
      const float mnew = fmaxf(mrun, cmax);
      const float alpha = __builtin_amdgcn_exp2f((mrun - mnew) * KS);
      lsum *= alpha;
#pragma unroll
      for (int r = 0; r < 16; r++) {
        const int row = (r & 3) + ((r >> 2) << 3) + (hi << 2);
        const float ar = __shfl(alpha, row);
        o0[r] *= ar;
        o1[r] *= ar;
      }
      mrun = mnew;
    }

    float pr[16];
    const float mk = mrun * KS;
#pragma unroll
    for (int r = 0; r < 16; r++)
      pr[r] = __builtin_amdgcn_exp2f(__builtin_fmaf(s[r], KS, -mk));
    float c01 = (pr[0] + pr[1]) + (pr[2] + pr[3]);
    float c23 = (pr[4] + pr[5]) + (pr[6] + pr[7]);
    float c45 = (pr[8] + pr[9]) + (pr[10] + pr[11]);
    float c67 = (pr[12] + pr[13]) + (pr[14] + pr[15]);
    float csum = (c01 + c23) + (c45 + c67);
    {
      int2v ss = pl32(__float_as_int(csum), __float_as_int(csum));
      csum = __int_as_float(ss.x) + __int_as_float(ss.y);
    }
    lsum += csum;

    // pack P -> bf16 PV A-fragments via permlane32_swap
    const uint32_t c0 = cvtpk(pr[0], pr[1]),   c1 = cvtpk(pr[2], pr[3]);
    const uint32_t c2 = cvtpk(pr[4], pr[5]),   c3 = cvtpk(pr[6], pr[7]);
    const uint32_t c4 = cvtpk(pr[8], pr[9]),   c5 = cvtpk(pr[10], pr[11]);
    const uint32_t c6 = cvtpk(pr[12], pr[13]), c7 = cvtpk(pr[14], pr[15]);
    int2v s02 = pl32((int)c0, (int)c2);
    int2v s13 = pl32((int)c1, (int)c3);
    int2v s46 = pl32((int)c4, (int)c6);
    int2v s57 = pl32((int)c5, (int)c7);
    union { uint32_t u[4]; short8 v; } pa, pb;
    pa.u[0] = (uint32_t)s02.x; pa.u[1] = (uint32_t)s13.x;
    pa.u[2] = (uint32_t)s02.y; pa.u[3] = (uint32_t)s13.y;
    pb.u[0] = (uint32_t)s46.x; pb.u[1] = (uint32_t)s57.x;
    pb.u[2] = (uint32_t)s46.y; pb.u[3] = (uint32_t)s57.y;

    // PV
    __builtin_amdgcn_s_setprio(1);
    o0 = __builtin_amdgcn_mfma_f32_32x32x16_bf16(pa.v, vc[0], o0, 0, 0, 0);
    o0 = __builtin_amdgcn_mfma_f32_32x32x16_bf16(pb.v, vc[1], o0, 0, 0, 0);
    o1 = __builtin_amdgcn_mfma_f32_32x32x16_bf16(pa.v, vc[2], o1, 0, 0, 0);
    o1 = __builtin_amdgcn_mfma_f32_32x32x16_bf16(pb.v, vc[3], o1, 0, 0, 0);
    __builtin_amdgcn_s_setprio(0);

    __syncthreads();  // drains stage (vmcnt 0) + this wave's ds_reads (lgkmcnt 0)
  }

  const int b = bh >> 4, h = bh & 15;
#pragma unroll
  for (int r = 0; r < 16; r++) {
    const int row = (r & 3) + ((r >> 2) << 3) + (hi << 2);
    const float lr = __shfl(lsum, row);
    const float inv = __builtin_amdgcn_rcpf(lr);
    const size_t base = ((size_t)b * 2048 + q0 + row) * 1024 + h * 64 + lo;
    O[base] = f2bf(o0[r] * inv);
    O[base + 32] = f2bf(o1[r] * inv);
  }
}

// ---------------- LayerNorm (residual already folded into fc by gemmfc) ----------------
__global__ __launch_bounds__(256) void ln_kernel(const float* __restrict__ fc,
                                                 const float* __restrict__ gamma,
                                                 const float* __restrict__ beta,
                                                 float* __restrict__ out) {
  const int m = blockIdx.x;
  const int t = threadIdx.x;
  const size_t base = (size_t)m * 1024 + t * 4;
  float4 x = *reinterpret_cast<const float4*>(fc + base);
  float s1 = x.x + x.y + x.z + x.w;
  float s2 = x.x * x.x + x.y * x.y + x.z * x.z + x.w * x.w;
#pragma unroll
  for (int off = 1; off < 64; off <<= 1) {
    s1 += __shfl_xor(s1, off);
    s2 += __shfl_xor(s2, off);
  }
  __shared__ float sh[8];
  const int w = t >> 6, lane = t & 63;
  if (lane == 0) { sh[w] = s1; sh[4 + w] = s2; }
  __syncthreads();
  s1 = sh[0] + sh[1] + sh[2] + sh[3];
  s2 = sh[4] + sh[5] + sh[6] + sh[7];
  const float mu = s1 * (1.0f / 1024.0f);
  const float var = s2 * (1.0f / 1024.0f) - mu * mu;
  const float rs = rsqrtf(var + 1e-6f);
  const float4 g = *reinterpret_cast<const float4*>(gamma + t * 4);
  const float4 be = *reinterpret_cast<const float4*>(beta + t * 4);
  float4 y;
  y.x = (x.x - mu) * rs * g.x + be.x;
  y.y = (x.y - mu) * rs * g.y + be.y;
  y.z = (x.z - mu) * rs * g.z + be.z;
  y.w = (x.w - mu) * rs * g.w + be.w;
  *reinterpret_cast<float4*>(out + base) = y;
}

__global__ void sentinel_kernel(float* out, int n) {
  int i = blockIdx.x * blockDim.x + threadIdx.x;
  if (i < n) out[i] = 1234.5f;
}

extern "C" void kernel_launch(void* const* d_in, const int* in_sizes, int n_in,
                              void* d_out, int out_size, void* d_ws, size_t ws_size,
                              hipStream_t stream) {
  const size_t MB = 1024ull * 1024ull;
  if (ws_size < 174 * MB) {  // distinctive failure mode if scratch too small
    sentinel_kernel<<<(out_size + 255) / 256, 256, 0, stream>>>((float*)d_out, out_size);
    return;
  }
  const float* fin[6];
  for (int i = 0; i < 6; i++) fin[i] = (const float*)d_in[i];
  const float* Wf[7];
  for (int i = 0; i < 7; i++) Wf[i] = (const float*)d_in[6 + i];
  const float* gamma = (const float*)d_in[13];
  const float* beta = (const float*)d_in[14];

  char* ws = (char*)d_ws;
  unsigned short* WqT = (unsigned short*)(ws + 96 * MB);   // [1024][2048]
  unsigned short* WkT = (unsigned short*)(ws + 100 * MB);
  unsigned short* WvT = (unsigned short*)(ws + 104 * MB);
  unsigned short* WfcT = (unsigned short*)(ws + 108 * MB); // [1024][1024]
  unsigned short* Qb = (unsigned short*)(ws + 110 * MB);   // [64][2048][64]
  unsigned short* Kb = (unsigned short*)(ws + 126 * MB);
  unsigned short* Vtb = (unsigned short*)(ws + 142 * MB);  // [64][64][64][32] tiled
  unsigned short* Ob = (unsigned short*)(ws + 158 * MB);   // [8192][1024]
  float* fcout = (float*)(ws + 16 * MB);

  TcvtArgs ta;
  const int wsel[7] = {0, 3, 1, 4, 2, 5, 6};
  unsigned short* wdst[7] = {WqT, WqT, WkT, WkT, WvT, WvT, WfcT};
  for (int i = 0; i < 7; i++) {
    ta.src[i] = Wf[wsel[i]];
    ta.dst[i] = wdst[i];
    ta.stride[i] = (i < 6) ? 2048 : 1024;
    ta.koff[i] = (i < 6) ? ((i & 1) ? 1024 : 0) : 0;
  }
  tcvt_kernel<<<dim3(32, 32, 7), 256, 0, stream>>>(ta);

  G3Args g3;
  g3.A1[0] = fin[0]; g3.A2[0] = fin[3]; g3.WT[0] = WqT; g3.out[0] = Qb;
  g3.A1[1] = fin[1]; g3.A2[1] = fin[4]; g3.WT[1] = WkT; g3.out[1] = Kb;
  g3.A1[2] = fin[2]; g3.A2[2] = fin[5]; g3.WT[2] = WvT; g3.out[2] = Vtb;
  gemm3_kernel<<<1536, 256, 0, stream>>>(g3);

  attn_kernel<<<1024, 256, 0, stream>>>(Qb, Kb, Vtb, Ob);

  gemmfc_kernel<<<512, 256, 0, stream>>>(Ob, WfcT, fin[0], fin[3], fcout);

  ln_kernel<<<8192, 256, 0, stream>>>(fcout, gamma, beta, (float*)d_out);
}

// Round 7
// 350.452 us; speedup vs baseline: 1.0652x; 1.0456x over previous
//
#include <hip/hip_runtime.h>
#include <hip/hip_bf16.h>
#include <stdint.h>

typedef __attribute__((ext_vector_type(4))) float f32x4;
typedef __attribute__((ext_vector_type(16))) float f32x16;
typedef __attribute__((ext_vector_type(8))) short short8;
typedef __attribute__((ext_vector_type(2))) int int2v;

#define DEV static __device__ __forceinline__

DEV unsigned short f2bf(float f) {
  unsigned u = __float_as_uint(f);
  u += 0x7fffu + ((u >> 16) & 1u);
  return (unsigned short)(u >> 16);
}

DEV uint32_t cvtpk(float a, float b) {  // {lo: bf16(a), hi: bf16(b)}, RNE
  uint32_t r;
  asm("v_cvt_pk_bf16_f32 %0, %1, %2" : "=v"(r) : "v"(a), "v"(b));
  return r;
}

// v_permlane32_swap_b32: r.x = {a[0:31], b[0:31] in hi lanes}, r.y = {a[32:63] in lo lanes, b[32:63]}
DEV int2v pl32(int a, int b) {
  return __builtin_amdgcn_permlane32_swap(a, b, false, false);
}

typedef const __attribute__((address_space(1))) void* gas_ptr;
typedef __attribute__((address_space(3))) void* las_ptr;

DEV void gload_lds16(const void* g, void* l) {
  __builtin_amdgcn_global_load_lds((gas_ptr)g, (las_ptr)l, 16, 0, 0);
}

// ---------------- f32 -> bf16 elementwise convert, all 6 tensors in one launch ----------------
// 8 elements per thread-iter (two float4 reads, one 16B store, 4x v_cvt_pk) — R6 analysis:
// the 4-wide version ran 301MB at only 4.0 TB/s (instruction-issue-bound); halving the
// memory-instruction count targets the ~6.3 TB/s streaming ceiling.
struct CvtArgs {
  const float* in[6];
  unsigned short* out[6];
};

__global__ __launch_bounds__(256) void cvt_kernel(CvtArgs a, int n8) {
  const float* __restrict__ in = a.in[blockIdx.y];
  unsigned short* __restrict__ out = a.out[blockIdx.y];
  int idx = blockIdx.x * blockDim.x + threadIdx.x;
  int stride = gridDim.x * blockDim.x;
  for (int i = idx; i < n8; i += stride) {
    const float4 v0 = reinterpret_cast<const float4*>(in)[2 * i];
    const float4 v1 = reinterpret_cast<const float4*>(in)[2 * i + 1];
    union { uint32_t u[4]; short8 v; } o;
    o.u[0] = cvtpk(v0.x, v0.y);
    o.u[1] = cvtpk(v0.z, v0.w);
    o.u[2] = cvtpk(v1.x, v1.y);
    o.u[3] = cvtpk(v1.z, v1.w);
    reinterpret_cast<short8*>(out)[i] = o.v;
  }
}

// ------------- weight transpose+convert: src f32 [1024 k][1024 n] -> dst bf16 [n][k], 7 in one ----
struct TcvtArgs {
  const float* src[7];
  unsigned short* dst[7];
  int stride[7];
  int koff[7];
};

__global__ __launch_bounds__(256) void tcvt_kernel(TcvtArgs a) {
  const int which = blockIdx.z;
  const float* __restrict__ src = a.src[which];
  unsigned short* __restrict__ dst = a.dst[which];
  const int dstStride = a.stride[which], kOff = a.koff[which];
  __shared__ float tile[32][33];
  int tx = threadIdx.x & 31;   // 0..31
  int ty = threadIdx.x >> 5;   // 0..7
  int n0 = blockIdx.x * 32;
  int k0 = blockIdx.y * 32;
#pragma unroll
  for (int i = 0; i < 4; i++)
    tile[ty + 8 * i][tx] = src[(size_t)(k0 + ty + 8 * i) * 1024 + n0 + tx];
  __syncthreads();
#pragma unroll
  for (int i = 0; i < 4; i++) {
    int n = n0 + ty + 8 * i;
    dst[(size_t)n * dstStride + kOff + k0 + tx] = f2bf(tile[tx][ty + 8 * i]);
  }
}

// ---------------- merged Q/K/V projection GEMM (proven 128^2 structure, bf16 A) ----------------
// C[8192 x 1024] = concat_k(A1,A2) @ W  (W transposed [n][k], Ktot=2048, ksplit=1024)
// R4-R6 lesson: fusing the f32->bf16 A-convert into this kernel loses (228us vs 48+136 split) —
// reg-staging puts HBM latency on the K-loop critical path; f32-in-LDS doubles staging traffic.
// Keep the split cvt + bf16 global_load_lds transport (TLP-covered barrier drain).
struct G3Args {
  const unsigned short* A1[3];
  const unsigned short* A2[3];
  const unsigned short* WT[3];
  unsigned short* out[3];
};

__global__ __launch_bounds__(256) void gemm3_kernel(G3Args g) {
  __shared__ unsigned short As[128 * 32];
  __shared__ unsigned short Bs[128 * 32];
  const int orig = blockIdx.x;
  const int swz = (orig & 7) * 192 + (orig >> 3);  // 1536 blocks, bijective
  const int which = swz >> 9;
  const int bid = swz & 511;
  const unsigned short* __restrict__ A1 = g.A1[which];
  const unsigned short* __restrict__ A2 = g.A2[which];
  const unsigned short* __restrict__ WT = g.WT[which];
  unsigned short* __restrict__ outp = g.out[which];

  const int tid = threadIdx.x;
  const int lane = tid & 63;
  const int w = tid >> 6;
  const int mt = bid >> 3, nt = bid & 7;
  const int m0 = mt * 128, n0 = nt * 128;

  const int srow = (w << 4) + (lane >> 2);
  const int scol = (lane & 3) << 3;

  f32x4 zero4 = {0.f, 0.f, 0.f, 0.f};
  f32x4 acc[4][4];
#pragma unroll
  for (int mi = 0; mi < 4; mi++)
#pragma unroll
    for (int ni = 0; ni < 4; ni++) acc[mi][ni] = zero4;

  const int wr = w >> 1, wc = w & 1;
  const int arow = (wr << 6) + (lane & 15);
  const int brow = (wc << 6) + (lane & 15);
  const int kcol = (lane >> 4) << 3;

  for (int kt = 0; kt < 64; kt++) {
    const int kk = kt << 5;
    const unsigned short* Asrc;
    int ka;
    if (kk < 1024) { Asrc = A1; ka = kk; } else { Asrc = A2; ka = kk - 1024; }
#pragma unroll
    for (int p = 0; p < 2; p++) {
      const unsigned short* gp = Asrc + (size_t)(m0 + p * 64 + srow) * 1024 + ka + scol;
      gload_lds16(gp, &As[(p * 64 + srow) * 32 + scol]);
    }
#pragma unroll
    for (int p = 0; p < 2; p++) {
      const unsigned short* gp = WT + (size_t)(n0 + p * 64 + srow) * 2048 + kk + scol;
      gload_lds16(gp, &Bs[(p * 64 + srow) * 32 + scol]);
    }
    __syncthreads();

    short8 av[4], bv[4];
#pragma unroll
    for (int mi = 0; mi < 4; mi++)
      av[mi] = *reinterpret_cast<const short8*>(&As[(arow + mi * 16) * 32 + kcol]);
#pragma unroll
    for (int ni = 0; ni < 4; ni++)
      bv[ni] = *reinterpret_cast<const short8*>(&Bs[(brow + ni * 16) * 32 + kcol]);
#pragma unroll
    for (int mi = 0; mi < 4; mi++)
#pragma unroll
      for (int ni = 0; ni < 4; ni++)
        acc[mi][ni] = __builtin_amdgcn_mfma_f32_16x16x32_bf16(av[mi], bv[ni], acc[mi][ni], 0, 0, 0);
    __syncthreads();
  }

  // epilogue: D layout col = lane&15, row = (lane>>4)*4 + reg
#pragma unroll
  for (int mi = 0; mi < 4; mi++) {
#pragma unroll
    for (int ni = 0; ni < 4; ni++) {
      const int col = n0 + (wc << 6) + ni * 16 + (lane & 15);
      const int rbase = m0 + (wr << 6) + mi * 16 + ((lane >> 4) << 2);
      const int h = col >> 6, d = col & 63;
      if (which < 2) {
#pragma unroll
        for (int r = 0; r < 4; r++) {
          const int m = rbase + r;
          const int b = m >> 11, l = m & 2047;
          outp[((size_t)((b * 16 + h) * 2048 + l)) * 64 + d] = f2bf(acc[mi][ni][r]);
        }
      } else {
        // V tiled: [bh][l/32][d][l%32], tile = 64x32 = 4KB contiguous
        const int m = rbase;
        const int b = m >> 11, l = m & 2047;
        const int bh = b * 16 + h;
        ushort4 o;
        o.x = f2bf(acc[mi][ni][0]);
        o.y = f2bf(acc[mi][ni][1]);
        o.z = f2bf(acc[mi][ni][2]);
        o.w = f2bf(acc[mi][ni][3]);
        *reinterpret_cast<ushort4*>(
            outp + (size_t)(bh * 64 + (l >> 5)) * 2048 + d * 32 + (l & 31)) = o;
      }
    }
  }
}

// ---------------- fc GEMM: C[8192 x 1024] = A @ W + q_a + q_s (residual fused), f32 out -------
__global__ __launch_bounds__(256) void gemmfc_kernel(const unsigned short* __restrict__ A1,
                                                     const unsigned short* __restrict__ WT,
                                                     const float* __restrict__ qa,
                                                     const float* __restrict__ qs,
                                                     float* __restrict__ outp) {
  __shared__ unsigned short As[128 * 32];
  __shared__ unsigned short Bs[128 * 32];
  const int orig = blockIdx.x;
  const int bid = (orig & 7) * 64 + (orig >> 3);  // 512 blocks, bijective XCD chunk
  const int tid = threadIdx.x;
  const int lane = tid & 63;
  const int w = tid >> 6;
  const int mt = bid >> 3, nt = bid & 7;
  const int m0 = mt * 128, n0 = nt * 128;

  const int srow = (w << 4) + (lane >> 2);
  const int scol = (lane & 3) << 3;

  f32x4 zero4 = {0.f, 0.f, 0.f, 0.f};
  f32x4 acc[4][4];
#pragma unroll
  for (int mi = 0; mi < 4; mi++)
#pragma unroll
    for (int ni = 0; ni < 4; ni++) acc[mi][ni] = zero4;

  const int wr = w >> 1, wc = w & 1;
  const int arow = (wr << 6) + (lane & 15);
  const int brow = (wc << 6) + (lane & 15);
  const int kcol = (lane >> 4) << 3;

  for (int kt = 0; kt < 32; kt++) {
    const int kk = kt << 5;
#pragma unroll
    for (int p = 0; p < 2; p++) {
      const unsigned short* gp = A1 + (size_t)(m0 + p * 64 + srow) * 1024 + kk + scol;
      gload_lds16(gp, &As[(p * 64 + srow) * 32 + scol]);
    }
#pragma unroll
    for (int p = 0; p < 2; p++) {
      const unsigned short* gp = WT + (size_t)(n0 + p * 64 + srow) * 1024 + kk + scol;
      gload_lds16(gp, &Bs[(p * 64 + srow) * 32 + scol]);
    }
    __syncthreads();

    short8 av[4], bv[4];
#pragma unroll
    for (int mi = 0; mi < 4; mi++)
      av[mi] = *reinterpret_cast<const short8*>(&As[(arow + mi * 16) * 32 + kcol]);
#pragma unroll
    for (int ni = 0; ni < 4; ni++)
      bv[ni] = *reinterpret_cast<const short8*>(&Bs[(brow + ni * 16) * 32 + kcol]);
#pragma unroll
    for (int mi = 0; mi < 4; mi++)
#pragma unroll
      for (int ni = 0; ni < 4; ni++)
        acc[mi][ni] = __builtin_amdgcn_mfma_f32_16x16x32_bf16(av[mi], bv[ni], acc[mi][ni], 0, 0, 0);
    __syncthreads();
  }

#pragma unroll
  for (int mi = 0; mi < 4; mi++) {
#pragma unroll
    for (int ni = 0; ni < 4; ni++) {
      const int col = n0 + (wc << 6) + ni * 16 + (lane & 15);
      const int rbase = m0 + (wr << 6) + mi * 16 + ((lane >> 4) << 2);
#pragma unroll
      for (int r = 0; r < 4; r++) {
        const size_t idx = (size_t)(rbase + r) * 1024 + col;
        outp[idx] = acc[mi][ni][r] + qa[idx] + qs[idx];
      }
    }
  }
}

// ---------------- flash attention, LDS-staged K/V shared by 4 waves ----------------
// Q,K: bf16 [bh][l][64]; Vt: bf16 tiled [bh][l/32][d][l%32]; O: bf16 [b*2048+l][h*64+d]
__global__ __launch_bounds__(256) void attn_kernel(const unsigned short* __restrict__ Q,
                                                   const unsigned short* __restrict__ K,
                                                   const unsigned short* __restrict__ Vt,
                                                   unsigned short* __restrict__ O) {
  __shared__ unsigned short Ks[2][2048];
  __shared__ unsigned short Vs[2][2048];
  const int tid = threadIdx.x;
  const int lane = tid & 63;
  const int w = tid >> 6;      // 0..3 = q-tile
  const int n = blockIdx.x;
  const int bh = (n & 7) * 8 + (n >> 7);   // XCD c owns bh [8c, 8c+8): 4MB K/V per L2
  const int qg = (n >> 3) & 15;
  const int q0 = qg * 128 + w * 32;
  const int lo = lane & 31, hi = lane >> 5;

  const unsigned short* qp = Q + ((size_t)bh * 2048 + q0 + lo) * 64 + (hi << 3);
  short8 qf[4];
#pragma unroll
  for (int c = 0; c < 4; c++)
    qf[c] = *reinterpret_cast<const short8*>(qp + c * 16);

  f32x16 o0 = {0.f,0.f,0.f,0.f,0.f,0.f,0.f,0.f,0.f,0.f,0.f,0.f,0.f,0.f,0.f,0.f};
  f32x16 o1 = {0.f,0.f,0.f,0.f,0.f,0.f,0.f,0.f,0.f,0.f,0.f,0.f,0.f,0.f,0.f,0.f};
  float mrun = -1e30f, lsum = 0.0f;
  const float KS = 1.44269504088896f / 16.0f;  // log2(e)/SCALE

  const char* Kg = (const char*)(K + (size_t)bh * 2048 * 64);
  const char* Vg = (const char*)(Vt + (size_t)bh * 131072);

  const int p16 = tid * 16;
  const int lswz = p16 ^ (((p16 >> 7) & 7) << 4);  // logical byte within tile
  const int koff = lswz;                            // K: logical == global layout
  const int voff = (lswz >> 7) * 64 + ((lswz >> 6) & 1) * 2048 + (lswz & 63);

  const int sK = (lo & 7) << 4;
  int kix[4];
#pragma unroll
  for (int c = 0; c < 4; c++)
    kix[c] = ((lo * 128 + hi * 16 + c * 32) ^ sK) >> 1;   // K[key=lo][d=hi*8 + c*16]
  int vix[4];
  vix[0] = ((lo * 128 + hi * 16) ^ sK) >> 1;        // V[d=lo   ][key=hi*8]
  vix[1] = ((lo * 128 + 32 + hi * 16) ^ sK) >> 1;   // V[d=lo   ][key=hi*8+16]
  vix[2] = ((lo * 128 + 64 + hi * 16) ^ sK) >> 1;   // V[d=lo+32][key=hi*8]
  vix[3] = ((lo * 128 + 96 + hi * 16) ^ sK) >> 1;   // V[d=lo+32][key=hi*8+16]

  auto STAGE = [&](int kt, int buf) {
    gload_lds16(Kg + (size_t)kt * 4096 + koff, &Ks[buf][tid * 8]);
    gload_lds16(Vg + (size_t)kt * 4096 + voff, &Vs[buf][tid * 8]);
  };

  STAGE(0, 0);
  __syncthreads();

  for (int kt = 0; kt < 64; kt++) {
    const int buf = kt & 1;
    const int nx = (kt < 63) ? kt + 1 : 63;
    STAGE(nx, buf ^ 1);  // in flight across this iteration; drained by __syncthreads

    short8 kc[4], vc[4];
#pragma unroll
    for (int c = 0; c < 4; c++)
      kc[c] = *reinterpret_cast<const short8*>(&Ks[buf][kix[c]]);
#pragma unroll
    for (int c = 0; c < 4; c++)
      vc[c] = *reinterpret_cast<const short8*>(&Vs[buf][vix[c]]);

    // QK^T (swapped: A=K so D rows = keys, D cols = q)
    f32x16 s = {0.f,0.f,0.f,0.f,0.f,0.f,0.f,0.f,0.f,0.f,0.f,0.f,0.f,0.f,0.f,0.f};
    __builtin_amdgcn_s_setprio(1);
#pragma unroll
    for (int c = 0; c < 4; c++)
      s = __builtin_amdgcn_mfma_f32_32x32x16_bf16(kc[c], qf[c], s, 0, 0, 0);
    __builtin_amdgcn_s_setprio(0);

    // online softmax (defer-max T13); cross-lane merges via permlane32_swap
    float m01 = fmaxf(s[0], s[1]), m23 = fmaxf(s[2], s[3]);
    float m45 = fmaxf(s[4], s[5]), m67 = fmaxf(s[6], s[7]);
    float m89 = fmaxf(s[8], s[9]), mab = fmaxf(s[10], s[11]);
    float mcd = fmaxf(s[12], s[13]), mef = fmaxf(s[14], s[15]);
    float cmax = fmaxf(fmaxf(fmaxf(m01, m23), fmaxf(m45, m67)),
                       fmaxf(fmaxf(m89, mab), fmaxf(mcd, mef)));
    {
      int2v mm = pl32(__float_as_int(cmax), __float_as_int(cmax));
      cmax = fmaxf(__int_as_float(mm.x), __int_as_float(mm.y));
    }

    if (__any(cmax > mrun + 128.0f)) {  // 128 raw = 8 post-scale nats
      const float mnew = fmaxf(mrun, cmax);
      const float alpha = __builtin_amdgcn_exp2f((mrun - mnew) * KS);
      lsum *= alpha;
#pragma unroll
      for (int r = 0; r < 16; r++) {
        const int row = (r & 3) + ((r >> 2) << 3) + (hi << 2);
        const float ar = __shfl(alpha, row);
        o0[r] *= ar;
        o1[r] *= ar;
      }
      mrun = mnew;
    }

    float pr[16];
    const float mk = mrun * KS;
#pragma unroll
    for (int r = 0; r < 16; r++)
      pr[r] = __builtin_amdgcn_exp2f(__builtin_fmaf(s[r], KS, -mk));
    float c01 = (pr[0] + pr[1]) + (pr[2] + pr[3]);
    float c23 = (pr[4] + pr[5]) + (pr[6] + pr[7]);
    float c45 = (pr[8] + pr[9]) + (pr[10] + pr[11]);
    float c67 = (pr[12] + pr[13]) + (pr[14] + pr[15]);
    float csum = (c01 + c23) + (c45 + c67);
    {
      int2v ss = pl32(__float_as_int(csum), __float_as_int(csum));
      csum = __int_as_float(ss.x) + __int_as_float(ss.y);
    }
    lsum += csum;

    // pack P -> bf16 PV A-fragments via permlane32_swap
    const uint32_t c0 = cvtpk(pr[0], pr[1]),   c1 = cvtpk(pr[2], pr[3]);
    const uint32_t c2 = cvtpk(pr[4], pr[5]),   c3 = cvtpk(pr[6], pr[7]);
    const uint32_t c4 = cvtpk(pr[8], pr[9]),   c5 = cvtpk(pr[10], pr[11]);
    const uint32_t c6 = cvtpk(pr[12], pr[13]), c7 = cvtpk(pr[14], pr[15]);
    int2v s02 = pl32((int)c0, (int)c2);
    int2v s13 = pl32((int)c1, (int)c3);
    int2v s46 = pl32((int)c4, (int)c6);
    int2v s57 = pl32((int)c5, (int)c7);
    union { uint32_t u[4]; short8 v; } pa, pb;
    pa.u[0] = (uint32_t)s02.x; pa.u[1] = (uint32_t)s13.x;
    pa.u[2] = (uint32_t)s02.y; pa.u[3] = (uint32_t)s13.y;
    pb.u[0] = (uint32_t)s46.x; pb.u[1] = (uint32_t)s57.x;
    pb.u[2] = (uint32_t)s46.y; pb.u[3] = (uint32_t)s57.y;

    // PV
    __builtin_amdgcn_s_setprio(1);
    o0 = __builtin_amdgcn_mfma_f32_32x32x16_bf16(pa.v, vc[0], o0, 0, 0, 0);
    o0 = __builtin_amdgcn_mfma_f32_32x32x16_bf16(pb.v, vc[1], o0, 0, 0, 0);
    o1 = __builtin_amdgcn_mfma_f32_32x32x16_bf16(pa.v, vc[2], o1, 0, 0, 0);
    o1 = __builtin_amdgcn_mfma_f32_32x32x16_bf16(pb.v, vc[3], o1, 0, 0, 0);
    __builtin_amdgcn_s_setprio(0);

    __syncthreads();  // drains stage (vmcnt 0) + this wave's ds_reads (lgkmcnt 0)
  }

  const int b = bh >> 4, h = bh & 15;
#pragma unroll
  for (int r = 0; r < 16; r++) {
    const int row = (r & 3) + ((r >> 2) << 3) + (hi << 2);
    const float lr = __shfl(lsum, row);
    const float inv = __builtin_amdgcn_rcpf(lr);
    const size_t base = ((size_t)b * 2048 + q0 + row) * 1024 + h * 64 + lo;
    O[base] = f2bf(o0[r] * inv);
    O[base + 32] = f2bf(o1[r] * inv);
  }
}

// ---------------- LayerNorm (residual already folded into fc by gemmfc) ----------------
__global__ __launch_bounds__(256) void ln_kernel(const float* __restrict__ fc,
                                                 const float* __restrict__ gamma,
                                                 const float* __restrict__ beta,
                                                 float* __restrict__ out) {
  const int m = blockIdx.x;
  const int t = threadIdx.x;
  const size_t base = (size_t)m * 1024 + t * 4;
  float4 x = *reinterpret_cast<const float4*>(fc + base);
  float s1 = x.x + x.y + x.z + x.w;
  float s2 = x.x * x.x + x.y * x.y + x.z * x.z + x.w * x.w;
#pragma unroll
  for (int off = 1; off < 64; off <<= 1) {
    s1 += __shfl_xor(s1, off);
    s2 += __shfl_xor(s2, off);
  }
  __shared__ float sh[8];
  const int w = t >> 6, lane = t & 63;
  if (lane == 0) { sh[w] = s1; sh[4 + w] = s2; }
  __syncthreads();
  s1 = sh[0] + sh[1] + sh[2] + sh[3];
  s2 = sh[4] + sh[5] + sh[6] + sh[7];
  const float mu = s1 * (1.0f / 1024.0f);
  const float var = s2 * (1.0f / 1024.0f) - mu * mu;
  const float rs = rsqrtf(var + 1e-6f);
  const float4 g = *reinterpret_cast<const float4*>(gamma + t * 4);
  const float4 be = *reinterpret_cast<const float4*>(beta + t * 4);
  float4 y;
  y.x = (x.x - mu) * rs * g.x + be.x;
  y.y = (x.y - mu) * rs * g.y + be.y;
  y.z = (x.z - mu) * rs * g.z + be.z;
  y.w = (x.w - mu) * rs * g.w + be.w;
  *reinterpret_cast<float4*>(out + base) = y;
}

__global__ void sentinel_kernel(float* out, int n) {
  int i = blockIdx.x * blockDim.x + threadIdx.x;
  if (i < n) out[i] = 1234.5f;
}

extern "C" void kernel_launch(void* const* d_in, const int* in_sizes, int n_in,
                              void* d_out, int out_size, void* d_ws, size_t ws_size,
                              hipStream_t stream) {
  const size_t MB = 1024ull * 1024ull;
  if (ws_size < 174 * MB) {  // distinctive failure mode if scratch too small
    sentinel_kernel<<<(out_size + 255) / 256, 256, 0, stream>>>((float*)d_out, out_size);
    return;
  }
  const float* fin[6];
  for (int i = 0; i < 6; i++) fin[i] = (const float*)d_in[i];
  const float* Wf[7];
  for (int i = 0; i < 7; i++) Wf[i] = (const float*)d_in[6 + i];
  const float* gamma = (const float*)d_in[13];
  const float* beta = (const float*)d_in[14];

  char* ws = (char*)d_ws;
  unsigned short* Abf[6];
  for (int i = 0; i < 6; i++) Abf[i] = (unsigned short*)(ws + (size_t)i * 16 * MB);
  unsigned short* WqT = (unsigned short*)(ws + 96 * MB);   // [1024][2048]
  unsigned short* WkT = (unsigned short*)(ws + 100 * MB);
  unsigned short* WvT = (unsigned short*)(ws + 104 * MB);
  unsigned short* WfcT = (unsigned short*)(ws + 108 * MB); // [1024][1024]
  unsigned short* Qb = (unsigned short*)(ws + 110 * MB);   // [64][2048][64]
  unsigned short* Kb = (unsigned short*)(ws + 126 * MB);
  unsigned short* Vtb = (unsigned short*)(ws + 142 * MB);  // [64][64][64][32] tiled
  unsigned short* Ob = (unsigned short*)(ws + 158 * MB);   // [8192][1024]
  float* fcout = (float*)(ws + 16 * MB);  // aliases Abf[1],Abf[2] (dead after proj GEMMs)

  CvtArgs ca;
  for (int i = 0; i < 6; i++) { ca.in[i] = fin[i]; ca.out[i] = Abf[i]; }
  cvt_kernel<<<dim3(1024, 6), 256, 0, stream>>>(ca, 1048576);

  TcvtArgs ta;
  const int wsel[7] = {0, 3, 1, 4, 2, 5, 6};
  unsigned short* wdst[7] = {WqT, WqT, WkT, WkT, WvT, WvT, WfcT};
  for (int i = 0; i < 7; i++) {
    ta.src[i] = Wf[wsel[i]];
    ta.dst[i] = wdst[i];
    ta.stride[i] = (i < 6) ? 2048 : 1024;
    ta.koff[i] = (i < 6) ? ((i & 1) ? 1024 : 0) : 0;
  }
  tcvt_kernel<<<dim3(32, 32, 7), 256, 0, stream>>>(ta);

  G3Args g3;
  g3.A1[0] = Abf[0]; g3.A2[0] = Abf[3]; g3.WT[0] = WqT; g3.out[0] = Qb;
  g3.A1[1] = Abf[1]; g3.A2[1] = Abf[4]; g3.WT[1] = WkT; g3.out[1] = Kb;
  g3.A1[2] = Abf[2]; g3.A2[2] = Abf[5]; g3.WT[2] = WvT; g3.out[2] = Vtb;
  gemm3_kernel<<<1536, 256, 0, stream>>>(g3);

  attn_kernel<<<1024, 256, 0, stream>>>(Qb, Kb, Vtb, Ob);

  gemmfc_kernel<<<512, 256, 0, stream>>>(Ob, WfcT, fin[0], fin[3], fcout);

  ln_kernel<<<8192, 256, 0, stream>>>(fcout, gamma, beta, (float*)d_out);
}